// Round 7
// baseline (63.384 us; speedup 1.0000x reference)
//
#include <hip/hip_runtime.h>

typedef _Float16 half8 __attribute__((ext_vector_type(8)));
typedef _Float16 half4 __attribute__((ext_vector_type(4)));
typedef float f32x4 __attribute__((ext_vector_type(4)));

#define W 512
#define H 512
#define NPIX (16.0f*3.0f*512.0f*512.0f)
#define NACC 64
#define TSTR 56                 // TP fast-axis stride (fp16): 112 B = 28 banks, 16B-aligned
#define TPL (64*TSTR)           // one field plane: 64 cols x 56 rows

// Block = 32 out rows x 64 out cols.  Grid = 48 planes x 16 sy x 8 sx = 6144.
__global__ __launch_bounds__(256) void ssim_main(const float* __restrict__ pred,
                                                 const float* __restrict__ targ,
                                                 const float* __restrict__ win,
                                                 float* __restrict__ acc) {
    const int tid  = threadIdx.x;
    const int lane = tid & 63;
    const int wv   = tid >> 6;          // wave = col-tile (ct) for both passes
    const int lo   = lane & 15;
    const int hi   = lane >> 4;

    // XCD swizzle (6144 % 8 == 0): 768 contiguous tiles per XCD; sx fastest
    // so neighbors sharing row halos co-reside in one XCD's L2.
    const int b = (blockIdx.x & 7) * 768 + (blockIdx.x >> 3);
    const int sx = b & 7, sy = (b >> 3) & 15, nc = b >> 7;
    const int x0 = sx * 64, y0 = sy * 32;
    const float* P = pred + (size_t)nc * (W * H);
    const float* T = targ + (size_t)nc * (W * H);

    __shared__ __align__(16) _Float16 TP[4 * TPL];  // 0:mu1 1:mu2 2:q 3:pt (transposed)
    __shared__ _Float16 gw[64];
    __shared__ float wsum[4];

    // gw[18+d] = g[d], d in [0,10]; zero elsewhere. g from row 5 of the window.
    if (tid < 64) {
        const int d = tid - 18;
        float val = 0.f;
        if (d >= 0 && d <= 10)
            val = win[55 + d] * __builtin_amdgcn_rcpf(sqrtf(win[60]));
        gw[tid] = (_Float16)val;
    }
    __syncthreads();

    // Weight B-fragments (k = hi*8+j convention, HW-validated in R6).
    half8 Bh, Bv;
    #pragma unroll
    for (int j = 0; j < 8; ++j) {
        Bh[j] = gw[15 + hi * 8 + j - lo];   // H band: g[k - n - 3]
        Bv[j] = gw[18 + hi * 8 + j - lo];   // V band: g[k - n]
    }

    const f32x4 zero4 = {0.f, 0.f, 0.f, 0.f};
    const int  cbase   = x0 + wv * 16 - 8 + hi * 8;  // lane's first input col
    const bool colsafe = (x0 + wv * 16 - 8 >= 0) && (x0 + wv * 16 + 23 < W);

    // ---- H-pass: 3 row-tiles of 16 input rows each (covers 42 halo rows). ----
    #pragma unroll
    for (int rt = 0; rt < 3; ++rt) {
        const int rowbase = y0 - 5 + rt * 16;
        const int row = rowbase + lo;        // lane's image row (A fragment m = lo)
        float pf[8], tf[8];
        if (colsafe && rowbase >= 0 && rowbase + 15 < H) {   // wave-uniform
            const float* Pp = P + (size_t)row * W + cbase;
            const float* Tp = T + (size_t)row * W + cbase;
            *(float4*)&pf[0] = *(const float4*)Pp;
            *(float4*)&pf[4] = *(const float4*)(Pp + 4);
            *(float4*)&tf[0] = *(const float4*)Tp;
            *(float4*)&tf[4] = *(const float4*)(Tp + 4);
        } else {
            const bool rok = (unsigned)row < H;
            const int  rid = rok ? row : 0;
            #pragma unroll
            for (int j = 0; j < 8; ++j) {
                const int  c  = cbase + j;
                const int  ci = ((unsigned)c < W) ? c : 0;
                const bool ok = rok && ((unsigned)c < W);
                const float pv = P[(size_t)rid * W + ci];
                const float tv = T[(size_t)rid * W + ci];
                pf[j] = ok ? pv : 0.f;       // zero padding
                tf[j] = ok ? tv : 0.f;
            }
        }
        half8 pa, ta, qa, xa;
        #pragma unroll
        for (int j = 0; j < 8; ++j) {
            pa[j] = (_Float16)pf[j];
            ta[j] = (_Float16)tf[j];
            qa[j] = (_Float16)fmaf(tf[j], tf[j], pf[j] * pf[j]);  // q = p^2+t^2
            xa[j] = (_Float16)(pf[j] * tf[j]);                    // x = p*t
        }
        f32x4 d0 = __builtin_amdgcn_mfma_f32_16x16x32_f16(pa, Bh, zero4, 0, 0, 0);
        f32x4 d1 = __builtin_amdgcn_mfma_f32_16x16x32_f16(ta, Bh, zero4, 0, 0, 0);
        f32x4 d2 = __builtin_amdgcn_mfma_f32_16x16x32_f16(qa, Bh, zero4, 0, 0, 0);
        f32x4 d3 = __builtin_amdgcn_mfma_f32_16x16x32_f16(xa, Bh, zero4, 0, 0, 0);
        // Transposed store: D col n = lo -> TP col, D rows hi*4+reg contiguous
        // along TP fast axis -> one ds_write_b64 per field.
        const int tbase = (wv * 16 + lo) * TSTR + rt * 16 + hi * 4;
        {
            half4 h0, h1, h2, h3;
            #pragma unroll
            for (int r = 0; r < 4; ++r) {
                h0[r] = (_Float16)d0[r]; h1[r] = (_Float16)d1[r];
                h2[r] = (_Float16)d2[r]; h3[r] = (_Float16)d3[r];
            }
            *(half4*)&TP[0 * TPL + tbase] = h0;
            *(half4*)&TP[1 * TPL + tbase] = h1;
            *(half4*)&TP[2 * TPL + tbase] = h2;
            *(half4*)&TP[3 * TPL + tbase] = h3;
        }
    }
    __syncthreads();

    // ---- V-pass + SSIM epilogue: 2 out row-tiles, A = one b128 per field. ----
    const float C1 = 1e-4f, C2 = 9e-4f;
    float sum = 0.f;
    #pragma unroll
    for (int rtv = 0; rtv < 2; ++rtv) {
        const int abase = (wv * 16 + lo) * TSTR + rtv * 16 + hi * 8;
        const half8 a0 = *(const half8*)&TP[0 * TPL + abase];
        const half8 a1 = *(const half8*)&TP[1 * TPL + abase];
        const half8 a2 = *(const half8*)&TP[2 * TPL + abase];
        const half8 a3 = *(const half8*)&TP[3 * TPL + abase];
        const f32x4 m1 = __builtin_amdgcn_mfma_f32_16x16x32_f16(a0, Bv, zero4, 0, 0, 0);
        const f32x4 m2 = __builtin_amdgcn_mfma_f32_16x16x32_f16(a1, Bv, zero4, 0, 0, 0);
        const f32x4 qq = __builtin_amdgcn_mfma_f32_16x16x32_f16(a2, Bv, zero4, 0, 0, 0);
        const f32x4 pt = __builtin_amdgcn_mfma_f32_16x16x32_f16(a3, Bv, zero4, 0, 0, 0);
        #pragma unroll
        for (int r = 0; r < 4; ++r) {
            const float mu1 = m1[r], mu2 = m2[r];
            const float ms  = fmaf(mu1, mu1, mu2 * mu2);   // mu1^2 + mu2^2
            const float m12 = mu1 * mu2;
            const float s12 = pt[r] - m12;                 // sigma12
            const float ssm = qq[r] - ms;                  // sigma1^2 + sigma2^2
            const float num = fmaf(2.f, m12, C1) * fmaf(2.f, s12, C2);
            const float den = (ms + C1) * (ssm + C2);
            sum += num * __builtin_amdgcn_rcpf(den);
        }
    }

    // Wave reduce -> block reduce -> one atomic per block (64 slots).
    #pragma unroll
    for (int off = 32; off > 0; off >>= 1) sum += __shfl_down(sum, off, 64);
    if (lane == 0) wsum[wv] = sum;
    __syncthreads();
    if (tid == 0)
        atomicAdd(&acc[blockIdx.x & (NACC - 1)], wsum[0] + wsum[1] + wsum[2] + wsum[3]);
}

__global__ void ssim_final(const float* __restrict__ acc, float* __restrict__ out) {
    float s = 0.f;
    #pragma unroll
    for (int i = 0; i < NACC; ++i) s += acc[i];
    out[0] = 0.1f * (1.0f - s / NPIX);
}

extern "C" void kernel_launch(void* const* d_in, const int* in_sizes, int n_in,
                              void* d_out, int out_size, void* d_ws, size_t ws_size,
                              hipStream_t stream) {
    const float* pred = (const float*)d_in[0];
    const float* targ = (const float*)d_in[1];
    const float* win  = (const float*)d_in[2];
    float* out = (float*)d_out;
    float* acc = (float*)d_ws;

    hipMemsetAsync(acc, 0, NACC * sizeof(float), stream);  // fresh accumulators
    ssim_main<<<6144, 256, 0, stream>>>(pred, targ, win, acc);
    ssim_final<<<1, 1, 0, stream>>>(acc, out);
}

// Round 8
// 62.620 us; speedup vs baseline: 1.0122x; 1.0122x over previous
//
#include <hip/hip_runtime.h>

typedef _Float16 half8 __attribute__((ext_vector_type(8)));
typedef _Float16 half4 __attribute__((ext_vector_type(4)));
typedef float f32x4 __attribute__((ext_vector_type(4)));

#define W 512
#define H 512
#define NPIX (16.0f*3.0f*512.0f*512.0f)
#define NACC 64
#define TSTR 88                 // TP fast-axis stride (fp16): 176 B -> uniform 2-way banks
#define TPL (64*TSTR)           // one field plane: 64 out-cols x 80 rows (+pad)

// Block = 64 out rows x 64 out cols.  Grid = 48 planes x 8 sy x 8 sx = 3072.
__global__ __launch_bounds__(256) void ssim_main(const float* __restrict__ pred,
                                                 const float* __restrict__ targ,
                                                 const float* __restrict__ win,
                                                 float* __restrict__ acc) {
    const int tid  = threadIdx.x;
    const int lane = tid & 63;
    const int wv   = tid >> 6;          // wave = out col-tile (16 cols) both passes
    const int lo   = lane & 15;
    const int hi   = lane >> 4;

    // XCD swizzle (3072 % 8 == 0): 384 contiguous tiles per XCD, sx fastest.
    const int b = (blockIdx.x & 7) * 384 + (blockIdx.x >> 3);
    const int sx = b & 7, sy = (b >> 3) & 7, nc = b >> 6;
    const int x0 = sx * 64, y0 = sy * 64;
    const float* P = pred + (size_t)nc * (W * H);
    const float* T = targ + (size_t)nc * (W * H);

    __shared__ __align__(16) _Float16 TP[4 * TPL];  // 0:mu1 1:mu2 2:q 3:pt (transposed)
    __shared__ _Float16 gw[64];
    __shared__ float wsum[4];

    // gw[18+d] = g[d] for d in [0,10], zero elsewhere (g from window row 5).
    if (tid < 64) {
        const int d = tid - 18;
        float val = 0.f;
        if (d >= 0 && d <= 10)
            val = win[55 + d] * __builtin_amdgcn_rcpf(sqrtf(win[60]));
        gw[tid] = (_Float16)val;
    }
    __syncthreads();

    // One band matrix serves BOTH passes: B[n][k] = g[k - n - 3]
    // (H: input col = base-8+k, out col = base+n; V: TP idx = 16rtv+k = outrow+3..+13).
    half8 Bw;
    #pragma unroll
    for (int j = 0; j < 8; ++j)
        Bw[j] = gw[15 + hi * 8 + j - lo];

    const f32x4 zero4 = {0.f, 0.f, 0.f, 0.f};
    const int  cbase   = x0 + wv * 16 - 8 + hi * 8;  // lane's first input col
    const bool colsafe = (x0 + wv * 16 - 8 >= 0) && (x0 + wv * 16 + 23 < W);

    // ---- H-pass prefetch: ALL 5 row-tiles' loads issued before any use. ----
    float pf[5][8], tf[5][8];
    #pragma unroll
    for (int rt = 0; rt < 5; ++rt) {
        const int rowbase = y0 - 8 + rt * 16;
        const int row = rowbase + lo;        // lane's image row (A fragment m = lo)
        if (colsafe && rowbase >= 0 && rowbase + 15 < H) {   // wave-uniform
            const float* Pp = P + (size_t)row * W + cbase;
            const float* Tp = T + (size_t)row * W + cbase;
            *(float4*)&pf[rt][0] = *(const float4*)Pp;
            *(float4*)&pf[rt][4] = *(const float4*)(Pp + 4);
            *(float4*)&tf[rt][0] = *(const float4*)Tp;
            *(float4*)&tf[rt][4] = *(const float4*)(Tp + 4);
        } else {
            const bool rok = (unsigned)row < H;
            const int  rid = rok ? row : 0;
            #pragma unroll
            for (int j = 0; j < 8; ++j) {
                const int  c  = cbase + j;
                const int  ci = ((unsigned)c < W) ? c : 0;
                const bool ok = rok && ((unsigned)c < W);
                const float pv = P[(size_t)rid * W + ci];
                const float tv = T[(size_t)rid * W + ci];
                pf[rt][j] = ok ? pv : 0.f;   // zero padding
                tf[rt][j] = ok ? tv : 0.f;
            }
        }
    }

    // ---- H-pass compute: cvt + 4 MFMA + transposed b64 stores per row-tile. ----
    #pragma unroll
    for (int rt = 0; rt < 5; ++rt) {
        half8 pa, ta, qa, xa;
        #pragma unroll
        for (int j = 0; j < 8; ++j) {
            const float p = pf[rt][j], t = tf[rt][j];
            pa[j] = (_Float16)p;
            ta[j] = (_Float16)t;
            qa[j] = (_Float16)fmaf(t, t, p * p);   // q = p^2 + t^2
            xa[j] = (_Float16)(p * t);             // x = p*t
        }
        const f32x4 d0 = __builtin_amdgcn_mfma_f32_16x16x32_f16(pa, Bw, zero4, 0, 0, 0);
        const f32x4 d1 = __builtin_amdgcn_mfma_f32_16x16x32_f16(ta, Bw, zero4, 0, 0, 0);
        const f32x4 d2 = __builtin_amdgcn_mfma_f32_16x16x32_f16(qa, Bw, zero4, 0, 0, 0);
        const f32x4 d3 = __builtin_amdgcn_mfma_f32_16x16x32_f16(xa, Bw, zero4, 0, 0, 0);
        // D: row m = hi*4+reg (H-conv'd image row), col n = lo (out col).
        // Transposed store: TP[outcol][rowidx], rowidx = 16rt + hi*4 + reg.
        const int tbase = (wv * 16 + lo) * TSTR + rt * 16 + hi * 4;
        half4 h0, h1, h2, h3;
        #pragma unroll
        for (int r = 0; r < 4; ++r) {
            h0[r] = (_Float16)d0[r]; h1[r] = (_Float16)d1[r];
            h2[r] = (_Float16)d2[r]; h3[r] = (_Float16)d3[r];
        }
        *(half4*)&TP[0 * TPL + tbase] = h0;
        *(half4*)&TP[1 * TPL + tbase] = h1;
        *(half4*)&TP[2 * TPL + tbase] = h2;
        *(half4*)&TP[3 * TPL + tbase] = h3;
    }
    __syncthreads();

    // ---- V-pass + SSIM epilogue: 4 out row-tiles per wave. ----
    // A[m=outcol(lo)][k] = TP[(16wv+lo)*TSTR + 16rtv + k]; B = Bw (same band);
    // out row = y0 + 16rtv + n, contribution g[k-n-3] over TP idx = outrow+3..+13.
    const float C1 = 1e-4f, C2 = 9e-4f;
    float sum = 0.f;
    #pragma unroll
    for (int rtv = 0; rtv < 4; ++rtv) {
        const int abase = (wv * 16 + lo) * TSTR + rtv * 16 + hi * 8;
        const half8 a0 = *(const half8*)&TP[0 * TPL + abase];
        const half8 a1 = *(const half8*)&TP[1 * TPL + abase];
        const half8 a2 = *(const half8*)&TP[2 * TPL + abase];
        const half8 a3 = *(const half8*)&TP[3 * TPL + abase];
        const f32x4 m1 = __builtin_amdgcn_mfma_f32_16x16x32_f16(a0, Bw, zero4, 0, 0, 0);
        const f32x4 m2 = __builtin_amdgcn_mfma_f32_16x16x32_f16(a1, Bw, zero4, 0, 0, 0);
        const f32x4 qq = __builtin_amdgcn_mfma_f32_16x16x32_f16(a2, Bw, zero4, 0, 0, 0);
        const f32x4 pt = __builtin_amdgcn_mfma_f32_16x16x32_f16(a3, Bw, zero4, 0, 0, 0);
        #pragma unroll
        for (int r = 0; r < 4; ++r) {
            const float mu1 = m1[r], mu2 = m2[r];
            const float ms  = fmaf(mu1, mu1, mu2 * mu2);   // mu1^2 + mu2^2
            const float m12 = mu1 * mu2;
            const float s12 = pt[r] - m12;                 // sigma12
            const float ssm = qq[r] - ms;                  // sigma1^2 + sigma2^2
            const float num = fmaf(2.f, m12, C1) * fmaf(2.f, s12, C2);
            const float den = (ms + C1) * (ssm + C2);
            sum += num * __builtin_amdgcn_rcpf(den);
        }
    }

    // Wave reduce -> block reduce -> one atomic per block (64 slots).
    #pragma unroll
    for (int off = 32; off > 0; off >>= 1) sum += __shfl_down(sum, off, 64);
    if (lane == 0) wsum[wv] = sum;
    __syncthreads();
    if (tid == 0)
        atomicAdd(&acc[blockIdx.x & (NACC - 1)], wsum[0] + wsum[1] + wsum[2] + wsum[3]);
}

__global__ void ssim_final(const float* __restrict__ acc, float* __restrict__ out) {
    float s = 0.f;
    #pragma unroll
    for (int i = 0; i < NACC; ++i) s += acc[i];
    out[0] = 0.1f * (1.0f - s / NPIX);
}

extern "C" void kernel_launch(void* const* d_in, const int* in_sizes, int n_in,
                              void* d_out, int out_size, void* d_ws, size_t ws_size,
                              hipStream_t stream) {
    const float* pred = (const float*)d_in[0];
    const float* targ = (const float*)d_in[1];
    const float* win  = (const float*)d_in[2];
    float* out = (float*)d_out;
    float* acc = (float*)d_ws;

    hipMemsetAsync(acc, 0, NACC * sizeof(float), stream);  // fresh accumulators
    ssim_main<<<3072, 256, 0, stream>>>(pred, targ, win, acc);
    ssim_final<<<1, 1, 0, stream>>>(acc, out);
}

// Round 9
// 57.975 us; speedup vs baseline: 1.0933x; 1.0801x over previous
//
#include <hip/hip_runtime.h>

typedef _Float16 half8 __attribute__((ext_vector_type(8)));
typedef _Float16 half4 __attribute__((ext_vector_type(4)));
typedef float f32x4 __attribute__((ext_vector_type(4)));

#define W 512
#define H 512
#define NPIX (16.0f*3.0f*512.0f*512.0f)
#define NACC 64
#define TSTR 88                 // TP fast-axis stride (fp16): 2-way banks only
#define TPL (64*TSTR)           // one field plane: 64 out-cols x 80 rows (+pad)

// Block = 64 out rows x 64 out cols, 512 threads (8 waves).
// Grid = 48 planes x 8 sy x 8 sx = 3072.
__global__ __launch_bounds__(512) void ssim_main(const float* __restrict__ pred,
                                                 const float* __restrict__ targ,
                                                 const float* __restrict__ win,
                                                 float* __restrict__ acc) {
    const int tid  = threadIdx.x;
    const int lane = tid & 63;
    const int wv   = tid >> 6;          // wave 0..7
    const int lo   = lane & 15;
    const int hi   = lane >> 4;

    // XCD swizzle (3072 % 8 == 0): 384 contiguous tiles per XCD, sx fastest.
    const int b = (blockIdx.x & 7) * 384 + (blockIdx.x >> 3);
    const int sx = b & 7, sy = (b >> 3) & 7, nc = b >> 6;
    const int x0 = sx * 64, y0 = sy * 64;
    const float* P = pred + (size_t)nc * (W * H);
    const float* T = targ + (size_t)nc * (W * H);

    __shared__ __align__(16) _Float16 TP[4 * TPL];  // 0:mu1 1:mu2 2:q 3:pt (transposed)
    __shared__ _Float16 gw[64];
    __shared__ float wsum[8];

    // gw[18+d] = g[d] for d in [0,10], zero elsewhere (g from window row 5).
    if (tid < 64) {
        const int d = tid - 18;
        float val = 0.f;
        if (d >= 0 && d <= 10)
            val = win[55 + d] * __builtin_amdgcn_rcpf(sqrtf(win[60]));
        gw[tid] = (_Float16)val;
    }
    __syncthreads();

    // One band matrix serves BOTH passes: B[n][k] = g[k - n - 3].
    half8 Bw;
    #pragma unroll
    for (int j = 0; j < 8; ++j)
        Bw[j] = gw[15 + hi * 8 + j - lo];

    const f32x4 zero4 = {0.f, 0.f, 0.f, 0.f};

    // ---- H-pass: 20 (rt,ct) tasks striped over 8 waves, no inner barriers. ----
    #pragma unroll
    for (int it = 0; it < 3; ++it) {
        const int t = wv + it * 8;
        if (t < 20) {                        // wave-uniform
            const int rt = t >> 2, ct = t & 3;
            const int cb0   = x0 + ct * 16 - 8;
            const int cbase = cb0 + hi * 8;  // lane's first input col
            const int rowbase = y0 - 8 + rt * 16;
            const int row = rowbase + lo;    // lane's image row (A fragment m = lo)
            float pf[8], tf[8];
            if (cb0 >= 0 && cb0 + 31 < W && rowbase >= 0 && rowbase + 15 < H) {
                const float* Pp = P + (size_t)row * W + cbase;
                const float* Tp = T + (size_t)row * W + cbase;
                *(float4*)&pf[0] = *(const float4*)Pp;
                *(float4*)&pf[4] = *(const float4*)(Pp + 4);
                *(float4*)&tf[0] = *(const float4*)Tp;
                *(float4*)&tf[4] = *(const float4*)(Tp + 4);
            } else {
                const bool rok = (unsigned)row < H;
                const int  rid = rok ? row : 0;
                #pragma unroll
                for (int j = 0; j < 8; ++j) {
                    const int  c  = cbase + j;
                    const int  ci = ((unsigned)c < W) ? c : 0;
                    const bool ok = rok && ((unsigned)c < W);
                    const float pv = P[(size_t)rid * W + ci];
                    const float tv = T[(size_t)rid * W + ci];
                    pf[j] = ok ? pv : 0.f;   // zero padding
                    tf[j] = ok ? tv : 0.f;
                }
            }
            half8 pa, ta, qa, xa;
            #pragma unroll
            for (int j = 0; j < 8; ++j) {
                const float p = pf[j], t2 = tf[j];
                pa[j] = (_Float16)p;
                ta[j] = (_Float16)t2;
                qa[j] = (_Float16)fmaf(t2, t2, p * p);   // q = p^2 + t^2
                xa[j] = (_Float16)(p * t2);              // x = p*t
            }
            const f32x4 d0 = __builtin_amdgcn_mfma_f32_16x16x32_f16(pa, Bw, zero4, 0, 0, 0);
            const f32x4 d1 = __builtin_amdgcn_mfma_f32_16x16x32_f16(ta, Bw, zero4, 0, 0, 0);
            const f32x4 d2 = __builtin_amdgcn_mfma_f32_16x16x32_f16(qa, Bw, zero4, 0, 0, 0);
            const f32x4 d3 = __builtin_amdgcn_mfma_f32_16x16x32_f16(xa, Bw, zero4, 0, 0, 0);
            // D: row m = hi*4+reg (image row), col n = lo (out col).
            // Transposed: TP[outcol][rowidx], rowidx = 16rt + hi*4 + reg.
            const int tbase = (ct * 16 + lo) * TSTR + rt * 16 + hi * 4;
            half4 h0, h1, h2, h3;
            #pragma unroll
            for (int r = 0; r < 4; ++r) {
                h0[r] = (_Float16)d0[r]; h1[r] = (_Float16)d1[r];
                h2[r] = (_Float16)d2[r]; h3[r] = (_Float16)d3[r];
            }
            *(half4*)&TP[0 * TPL + tbase] = h0;
            *(half4*)&TP[1 * TPL + tbase] = h1;
            *(half4*)&TP[2 * TPL + tbase] = h2;
            *(half4*)&TP[3 * TPL + tbase] = h3;
        }
    }
    __syncthreads();

    // ---- V-pass + SSIM epilogue: 16 tasks, 2 per wave. ----
    const float C1 = 1e-4f, C2 = 9e-4f;
    float sum = 0.f;
    #pragma unroll
    for (int iv = 0; iv < 2; ++iv) {
        const int v = wv + iv * 8;           // 0..15
        const int rtv = v >> 2, ct = v & 3;
        const int abase = (ct * 16 + lo) * TSTR + rtv * 16 + hi * 8;
        const half8 a0 = *(const half8*)&TP[0 * TPL + abase];
        const half8 a1 = *(const half8*)&TP[1 * TPL + abase];
        const half8 a2 = *(const half8*)&TP[2 * TPL + abase];
        const half8 a3 = *(const half8*)&TP[3 * TPL + abase];
        const f32x4 m1 = __builtin_amdgcn_mfma_f32_16x16x32_f16(a0, Bw, zero4, 0, 0, 0);
        const f32x4 m2 = __builtin_amdgcn_mfma_f32_16x16x32_f16(a1, Bw, zero4, 0, 0, 0);
        const f32x4 qq = __builtin_amdgcn_mfma_f32_16x16x32_f16(a2, Bw, zero4, 0, 0, 0);
        const f32x4 pt = __builtin_amdgcn_mfma_f32_16x16x32_f16(a3, Bw, zero4, 0, 0, 0);
        #pragma unroll
        for (int r = 0; r < 4; ++r) {
            const float mu1 = m1[r], mu2 = m2[r];
            const float ms  = fmaf(mu1, mu1, mu2 * mu2);   // mu1^2 + mu2^2
            const float m12 = mu1 * mu2;
            const float s12 = pt[r] - m12;                 // sigma12
            const float ssm = qq[r] - ms;                  // sigma1^2 + sigma2^2
            const float num = fmaf(2.f, m12, C1) * fmaf(2.f, s12, C2);
            const float den = (ms + C1) * (ssm + C2);
            sum += num * __builtin_amdgcn_rcpf(den);
        }
    }

    // Wave reduce -> block reduce -> one atomic per block (64 slots).
    #pragma unroll
    for (int off = 32; off > 0; off >>= 1) sum += __shfl_down(sum, off, 64);
    if (lane == 0) wsum[wv] = sum;
    __syncthreads();
    if (tid == 0) {
        float bsum = 0.f;
        #pragma unroll
        for (int w = 0; w < 8; ++w) bsum += wsum[w];
        atomicAdd(&acc[blockIdx.x & (NACC - 1)], bsum);
    }
}

__global__ void ssim_final(const float* __restrict__ acc, float* __restrict__ out) {
    float s = 0.f;
    #pragma unroll
    for (int i = 0; i < NACC; ++i) s += acc[i];
    out[0] = 0.1f * (1.0f - s / NPIX);
}

extern "C" void kernel_launch(void* const* d_in, const int* in_sizes, int n_in,
                              void* d_out, int out_size, void* d_ws, size_t ws_size,
                              hipStream_t stream) {
    const float* pred = (const float*)d_in[0];
    const float* targ = (const float*)d_in[1];
    const float* win  = (const float*)d_in[2];
    float* out = (float*)d_out;
    float* acc = (float*)d_ws;

    hipMemsetAsync(acc, 0, NACC * sizeof(float), stream);  // fresh accumulators
    ssim_main<<<3072, 512, 0, stream>>>(pred, targ, win, acc);
    ssim_final<<<1, 1, 0, stream>>>(acc, out);
}

// Round 10
// 42.966 us; speedup vs baseline: 1.4752x; 1.3493x over previous
//
#include <hip/hip_runtime.h>

typedef _Float16 half8 __attribute__((ext_vector_type(8)));
typedef _Float16 half4 __attribute__((ext_vector_type(4)));
typedef float f32x4 __attribute__((ext_vector_type(4)));

#define W 512
#define H 512
#define NPIX (16.0f*3.0f*512.0f*512.0f)
#define NACC 64
#define TPSTR 88                // TP fast-axis stride (fp16): 176B rows, 16B-aligned, spread banks
#define TPL (64*TPSTR)          // one field plane
#define ROWF 84                 // staged row stride in floats (80 real + 4 pad) = 21 chunks
#define TOFF 6720               // float offset of target array in stage (1680 chunks * 4)
#define SFLOATS 13568           // stage buffer floats = 3392 chunks * 4
#define NT 12                   // tiles per persistent block (3072 / 256)
#define NSLOT 7                 // max DMA instructions per wave per tile
#define NINST 53                // total DMA instructions per tile (ceil(3360/64))

#define VMCNT0() asm volatile("s_waitcnt vmcnt(0)" ::: "memory")
#define LGKM0()  asm volatile("s_waitcnt lgkmcnt(0)" ::: "memory")
#define BAR()    { asm volatile("" ::: "memory"); __builtin_amdgcn_s_barrier(); asm volatile("" ::: "memory"); }

__global__ __launch_bounds__(512) void ssim_main(const float* __restrict__ pred,
                                                 const float* __restrict__ targ,
                                                 const float* __restrict__ win,
                                                 float* __restrict__ ws) {
    const int tid  = threadIdx.x;
    const int lane = tid & 63;
    const int wv   = tid >> 6;          // wave 0..7
    const int lo   = lane & 15;
    const int hi   = lane >> 4;

    float* acc = ws;                    // 64 accumulator slots
    const float* zp = ws + 64;          // 256B zero page (memset by launch)

    __shared__ __align__(16) float stage[2][SFLOATS];   // 108.5 KB: pred+targ halo, dbuf
    __shared__ __align__(16) _Float16 TP[4 * TPL];      // 45 KB: 0:mu1 1:mu2 2:q 3:pt
    __shared__ _Float16 gw[64];
    __shared__ float wsum[8];

    // gw[18+d] = g[d] for d in [0,10], zero elsewhere (g from window row 5).
    if (tid < 64) {
        const int d = tid - 18;
        float val = 0.f;
        if (d >= 0 && d <= 10)
            val = win[55 + d] * __builtin_amdgcn_rcpf(sqrtf(win[60]));
        gw[tid] = (_Float16)val;
    }
    __syncthreads();

    // One band matrix serves BOTH passes: B[n][k] = g[k - n - 3] (R9-validated).
    half8 Bw;
    #pragma unroll
    for (int j = 0; j < 8; ++j)
        Bw[j] = gw[15 + hi * 8 + j - lo];

    // Per-slot DMA precompute (tile-invariant). Chunk id -> (array, row, colchunk):
    // id = inst*64 + lane; arr = id>=1680; cid = id - 1680*arr; r = cid/21; cc = cid%21.
    // cc==20 is the row-pad chunk, r>=80 is overflow: both source the zero page.
    int prow[NSLOT], pcol[NSLOT], parr[NSLOT];
    #pragma unroll
    for (int s = 0; s < NSLOT; ++s) {
        const int inst = s * 8 + wv;
        const int id   = inst * 64 + lane;
        const int arr  = (id >= 1680) ? 1 : 0;
        const int cid  = id - arr * 1680;
        const int r    = (cid * 3121) >> 16;     // exact /21 for cid < 2000
        const int cc   = cid - r * 21;
        const bool bad = (r >= 80) || (cc >= 20);
        prow[s] = bad ? 0x100000 : r;            // forces gy OOB -> zero page
        pcol[s] = cc * 4 - 8;
        parr[s] = arr;
    }

    // XCD swizzle (256 blocks, bijective): each XCD gets 32 consecutive blocks.
    const int b  = (blockIdx.x & 7) * 32 + (blockIdx.x >> 3);
    const int t0 = b * NT;
    float sum = 0.f;
    const f32x4 zero4 = {0.f, 0.f, 0.f, 0.f};

    auto STAGE = [&](int tidx, int buf) {
        const int nc = tidx >> 6, rem = tidx & 63;
        const int y0 = (rem >> 3) * 64, x0 = (rem & 7) * 64;
        const float* P  = pred + (size_t)nc * (W * H);
        const float* Tt = targ + (size_t)nc * (W * H);
        #pragma unroll
        for (int s = 0; s < NSLOT; ++s) {
            const int inst = s * 8 + wv;
            if (inst < NINST) {                  // wave-uniform
                const int gy = y0 - 8 + prow[s];
                const int gx = x0 + pcol[s];
                const bool ok = ((unsigned)gy < H) && ((unsigned)gx < W);
                const float* bp  = parr[s] ? Tt : P;
                const float* src = ok ? (bp + (gy * W + gx)) : zp;
                __builtin_amdgcn_global_load_lds(
                    (const __attribute__((address_space(1))) void*)src,
                    (__attribute__((address_space(3))) void*)&stage[buf][inst * 256],
                    16, 0, 0);
            }
        }
    };

    // ---- Prologue: stage tile 0, wait, barrier. ----
    STAGE(t0, 0);
    VMCNT0(); BAR();

    int cur = 0;
    #pragma unroll 1
    for (int i = 0; i < NT; ++i) {
        if (i + 1 < NT) STAGE(t0 + i + 1, cur ^ 1);   // DMA next tile (async, in flight)

        // ---- H-pass from stage[cur] -> TP (20 tasks over 8 waves). ----
        #pragma unroll
        for (int it = 0; it < 3; ++it) {
            const int t = wv + it * 8;
            if (t < 20) {                        // wave-uniform
                const int rt = t >> 2, ct = t & 3;
                const int row  = rt * 16 + lo;   // staged row (image row y0-8+row)
                const int coff = ct * 16 + hi * 8;
                const float* SP = &stage[cur][row * ROWF + coff];
                float pf[8], tf[8];
                *(float4*)&pf[0] = *(const float4*)SP;
                *(float4*)&pf[4] = *(const float4*)(SP + 4);
                *(float4*)&tf[0] = *(const float4*)(SP + TOFF);
                *(float4*)&tf[4] = *(const float4*)(SP + TOFF + 4);
                half8 pa, ta, qa, xa;
                #pragma unroll
                for (int j = 0; j < 8; ++j) {
                    const float p = pf[j], t2 = tf[j];
                    pa[j] = (_Float16)p;
                    ta[j] = (_Float16)t2;
                    qa[j] = (_Float16)fmaf(t2, t2, p * p);   // q = p^2 + t^2
                    xa[j] = (_Float16)(p * t2);              // x = p*t
                }
                const f32x4 d0 = __builtin_amdgcn_mfma_f32_16x16x32_f16(pa, Bw, zero4, 0, 0, 0);
                const f32x4 d1 = __builtin_amdgcn_mfma_f32_16x16x32_f16(ta, Bw, zero4, 0, 0, 0);
                const f32x4 d2 = __builtin_amdgcn_mfma_f32_16x16x32_f16(qa, Bw, zero4, 0, 0, 0);
                const f32x4 d3 = __builtin_amdgcn_mfma_f32_16x16x32_f16(xa, Bw, zero4, 0, 0, 0);
                const int tbase = (ct * 16 + lo) * TPSTR + rt * 16 + hi * 4;
                half4 h0, h1, h2, h3;
                #pragma unroll
                for (int r = 0; r < 4; ++r) {
                    h0[r] = (_Float16)d0[r]; h1[r] = (_Float16)d1[r];
                    h2[r] = (_Float16)d2[r]; h3[r] = (_Float16)d3[r];
                }
                *(half4*)&TP[0 * TPL + tbase] = h0;
                *(half4*)&TP[1 * TPL + tbase] = h1;
                *(half4*)&TP[2 * TPL + tbase] = h2;
                *(half4*)&TP[3 * TPL + tbase] = h3;
            }
        }
        LGKM0(); BAR();                          // TP complete; DMA still in flight

        // ---- V-pass + SSIM epilogue (16 tasks, 2 per wave). ----
        const float C1 = 1e-4f, C2 = 9e-4f;
        #pragma unroll
        for (int iv = 0; iv < 2; ++iv) {
            const int v = wv + iv * 8;
            const int rtv = v >> 2, ct = v & 3;
            const int abase = (ct * 16 + lo) * TPSTR + rtv * 16 + hi * 8;
            const half8 a0 = *(const half8*)&TP[0 * TPL + abase];
            const half8 a1 = *(const half8*)&TP[1 * TPL + abase];
            const half8 a2 = *(const half8*)&TP[2 * TPL + abase];
            const half8 a3 = *(const half8*)&TP[3 * TPL + abase];
            const f32x4 m1 = __builtin_amdgcn_mfma_f32_16x16x32_f16(a0, Bw, zero4, 0, 0, 0);
            const f32x4 m2 = __builtin_amdgcn_mfma_f32_16x16x32_f16(a1, Bw, zero4, 0, 0, 0);
            const f32x4 qq = __builtin_amdgcn_mfma_f32_16x16x32_f16(a2, Bw, zero4, 0, 0, 0);
            const f32x4 pt = __builtin_amdgcn_mfma_f32_16x16x32_f16(a3, Bw, zero4, 0, 0, 0);
            #pragma unroll
            for (int r = 0; r < 4; ++r) {
                const float mu1 = m1[r], mu2 = m2[r];
                const float ms  = fmaf(mu1, mu1, mu2 * mu2);
                const float m12 = mu1 * mu2;
                const float s12 = pt[r] - m12;
                const float ssm = qq[r] - ms;
                const float num = fmaf(2.f, m12, C1) * fmaf(2.f, s12, C2);
                const float den = (ms + C1) * (ssm + C2);
                sum += num * __builtin_amdgcn_rcpf(den);
            }
        }

        VMCNT0(); BAR();                         // next buffer fully staged; stage[cur] free
        cur ^= 1;
    }

    // ---- Reduce: wave -> block -> one atomic per block. ----
    #pragma unroll
    for (int off = 32; off > 0; off >>= 1) sum += __shfl_down(sum, off, 64);
    if (lane == 0) wsum[wv] = sum;
    __syncthreads();
    if (tid == 0) {
        float bs = 0.f;
        #pragma unroll
        for (int w2 = 0; w2 < 8; ++w2) bs += wsum[w2];
        atomicAdd(&acc[blockIdx.x & (NACC - 1)], bs);
    }
}

__global__ void ssim_final(const float* __restrict__ acc, float* __restrict__ out) {
    float s = 0.f;
    #pragma unroll
    for (int i = 0; i < NACC; ++i) s += acc[i];
    out[0] = 0.1f * (1.0f - s / NPIX);
}

extern "C" void kernel_launch(void* const* d_in, const int* in_sizes, int n_in,
                              void* d_out, int out_size, void* d_ws, size_t ws_size,
                              hipStream_t stream) {
    const float* pred = (const float*)d_in[0];
    const float* targ = (const float*)d_in[1];
    const float* win  = (const float*)d_in[2];
    float* out = (float*)d_out;
    float* ws  = (float*)d_ws;

    // 512B: 64 accumulator slots + 256B zero page (DMA source for OOB lanes).
    hipMemsetAsync(ws, 0, 512, stream);
    ssim_main<<<256, 512, 0, stream>>>(pred, targ, win, ws);
    ssim_final<<<1, 1, 0, stream>>>(ws, out);
}

// Round 11
// 40.625 us; speedup vs baseline: 1.5602x; 1.0576x over previous
//
#include <hip/hip_runtime.h>

typedef _Float16 half8 __attribute__((ext_vector_type(8)));
typedef _Float16 half4 __attribute__((ext_vector_type(4)));
typedef float f32x4 __attribute__((ext_vector_type(4)));

#define W 512
#define H 512
#define NPIX (16.0f*3.0f*512.0f*512.0f)
#define NACC 64
#define TPSTR 88                // TP fast-axis stride (fp16)
#define TPL (64*TPSTR)          // one field plane
#define ROWF 84                 // staged row stride in floats (80 real + 4 pad)
#define TOFF 6720               // float offset of target array inside a stage buffer
#define SFLOATS 13568           // stage buffer floats (3392 chunks * 4)
#define NT 12                   // tiles per persistent block (3072 / 256)
#define NSLOT 7                 // max DMA instructions per wave per tile
#define NINST 53                // total DMA instructions per tile

#define VMCNT0() asm volatile("s_waitcnt vmcnt(0)" ::: "memory")
#define LGKM0()  asm volatile("s_waitcnt lgkmcnt(0)" ::: "memory")
#define BAR()    { asm volatile("" ::: "memory"); __builtin_amdgcn_s_barrier(); asm volatile("" ::: "memory"); }

__global__ __launch_bounds__(512) void ssim_main(const float* __restrict__ pred,
                                                 const float* __restrict__ targ,
                                                 const float* __restrict__ win,
                                                 float* __restrict__ ws) {
    const int tid  = threadIdx.x;
    const int lane = tid & 63;
    const int wv   = tid >> 6;          // wave 0..7
    const int lo   = lane & 15;
    const int hi   = lane >> 4;

    float* acc = ws;                    // 64 accumulator slots
    const float* zp = ws + 64;          // 256B zero page

    // STATIC buffer names: provably disjoint -> no spurious vmcnt before
    // stage reads while the other buffer's DMA is in flight (R10 post-mortem).
    __shared__ __align__(16) float stageA[SFLOATS];
    __shared__ __align__(16) float stageB[SFLOATS];
    __shared__ __align__(16) _Float16 TP[4 * TPL];      // 0:mu1 1:mu2 2:q 3:pt
    __shared__ _Float16 gw[64];
    __shared__ float wsum[8];

    // gw[18+d] = g[d] for d in [0,10], zero elsewhere (g from window row 5).
    if (tid < 64) {
        const int d = tid - 18;
        float val = 0.f;
        if (d >= 0 && d <= 10)
            val = win[55 + d] * __builtin_amdgcn_rcpf(sqrtf(win[60]));
        gw[tid] = (_Float16)val;
    }
    __syncthreads();

    // One band matrix serves BOTH passes: B[n][k] = g[k - n - 3] (validated).
    half8 Bw;
    #pragma unroll
    for (int j = 0; j < 8; ++j)
        Bw[j] = gw[15 + hi * 8 + j - lo];

    // Per-slot DMA precompute (tile-invariant), verbatim from R10.
    int prow[NSLOT], pcol[NSLOT], parr[NSLOT];
    #pragma unroll
    for (int s = 0; s < NSLOT; ++s) {
        const int inst = s * 8 + wv;
        const int id   = inst * 64 + lane;
        const int arr  = (id >= 1680) ? 1 : 0;
        const int cid  = id - arr * 1680;
        const int r    = (cid * 3121) >> 16;     // exact /21 for cid < 2000
        const int cc   = cid - r * 21;
        const bool bad = (r >= 80) || (cc >= 20);
        prow[s] = bad ? 0x100000 : r;            // forces gy OOB -> zero page
        pcol[s] = cc * 4 - 8;
        parr[s] = arr;
    }

    // XCD swizzle (256 blocks): each XCD gets 32 consecutive blocks.
    const int b  = (blockIdx.x & 7) * 32 + (blockIdx.x >> 3);
    const int t0 = b * NT;
    float sum = 0.f;
    const f32x4 zero4 = {0.f, 0.f, 0.f, 0.f};
    const float C1 = 1e-4f, C2 = 9e-4f;

#define STAGE(tidx, BUF)                                                       \
    {                                                                          \
        const int nc = (tidx) >> 6, rem = (tidx) & 63;                         \
        const int y0 = (rem >> 3) * 64, x0 = (rem & 7) * 64;                   \
        const float* P  = pred + (size_t)nc * (W * H);                         \
        const float* Tt = targ + (size_t)nc * (W * H);                         \
        _Pragma("unroll")                                                      \
        for (int s = 0; s < NSLOT; ++s) {                                      \
            const int inst = s * 8 + wv;                                       \
            if (inst < NINST) {                                                \
                const int gy = y0 - 8 + prow[s];                               \
                const int gx = x0 + pcol[s];                                   \
                const bool ok = ((unsigned)gy < H) && ((unsigned)gx < W);      \
                const float* bp  = parr[s] ? Tt : P;                           \
                const float* src = ok ? (bp + (gy * W + gx)) : zp;             \
                __builtin_amdgcn_global_load_lds(                              \
                    (const __attribute__((address_space(1))) void*)src,        \
                    (__attribute__((address_space(3))) void*)&BUF[inst * 256], \
                    16, 0, 0);                                                 \
            }                                                                  \
        }                                                                      \
        __builtin_amdgcn_sched_barrier(0);  /* pin DMA issue-early */          \
    }

#define COMPUTE(BUF)                                                           \
    {                                                                          \
        _Pragma("unroll")                                                      \
        for (int it = 0; it < 3; ++it) {                                       \
            const int t = wv + it * 8;                                         \
            if (t < 20) {                                                      \
                const int rt = t >> 2, ct = t & 3;                             \
                const int row  = rt * 16 + lo;                                 \
                const int coff = ct * 16 + hi * 8;                             \
                const float* SP = &BUF[row * ROWF + coff];                     \
                float pf[8], tf[8];                                            \
                *(float4*)&pf[0] = *(const float4*)SP;                         \
                *(float4*)&pf[4] = *(const float4*)(SP + 4);                   \
                *(float4*)&tf[0] = *(const float4*)(SP + TOFF);                \
                *(float4*)&tf[4] = *(const float4*)(SP + TOFF + 4);            \
                half8 pa, ta, qa, xa;                                          \
                _Pragma("unroll")                                              \
                for (int j = 0; j < 8; ++j) {                                  \
                    const float p = pf[j], t2 = tf[j];                         \
                    pa[j] = (_Float16)p;                                       \
                    ta[j] = (_Float16)t2;                                      \
                    qa[j] = (_Float16)fmaf(t2, t2, p * p);                     \
                    xa[j] = (_Float16)(p * t2);                                \
                }                                                              \
                const f32x4 d0 = __builtin_amdgcn_mfma_f32_16x16x32_f16(pa, Bw, zero4, 0, 0, 0); \
                const f32x4 d1 = __builtin_amdgcn_mfma_f32_16x16x32_f16(ta, Bw, zero4, 0, 0, 0); \
                const f32x4 d2 = __builtin_amdgcn_mfma_f32_16x16x32_f16(qa, Bw, zero4, 0, 0, 0); \
                const f32x4 d3 = __builtin_amdgcn_mfma_f32_16x16x32_f16(xa, Bw, zero4, 0, 0, 0); \
                const int tbase = (ct * 16 + lo) * TPSTR + rt * 16 + hi * 4;   \
                half4 h0, h1, h2, h3;                                          \
                _Pragma("unroll")                                              \
                for (int r = 0; r < 4; ++r) {                                  \
                    h0[r] = (_Float16)d0[r]; h1[r] = (_Float16)d1[r];          \
                    h2[r] = (_Float16)d2[r]; h3[r] = (_Float16)d3[r];          \
                }                                                              \
                *(half4*)&TP[0 * TPL + tbase] = h0;                            \
                *(half4*)&TP[1 * TPL + tbase] = h1;                            \
                *(half4*)&TP[2 * TPL + tbase] = h2;                            \
                *(half4*)&TP[3 * TPL + tbase] = h3;                            \
            }                                                                  \
        }                                                                      \
        LGKM0(); BAR();                                                        \
        _Pragma("unroll")                                                      \
        for (int iv = 0; iv < 2; ++iv) {                                       \
            const int v = wv + iv * 8;                                         \
            const int rtv = v >> 2, ct = v & 3;                                \
            const int abase = (ct * 16 + lo) * TPSTR + rtv * 16 + hi * 8;      \
            const half8 a0 = *(const half8*)&TP[0 * TPL + abase];              \
            const half8 a1 = *(const half8*)&TP[1 * TPL + abase];              \
            const half8 a2 = *(const half8*)&TP[2 * TPL + abase];              \
            const half8 a3 = *(const half8*)&TP[3 * TPL + abase];              \
            const f32x4 m1 = __builtin_amdgcn_mfma_f32_16x16x32_f16(a0, Bw, zero4, 0, 0, 0); \
            const f32x4 m2 = __builtin_amdgcn_mfma_f32_16x16x32_f16(a1, Bw, zero4, 0, 0, 0); \
            const f32x4 qq = __builtin_amdgcn_mfma_f32_16x16x32_f16(a2, Bw, zero4, 0, 0, 0); \
            const f32x4 pt = __builtin_amdgcn_mfma_f32_16x16x32_f16(a3, Bw, zero4, 0, 0, 0); \
            _Pragma("unroll")                                                  \
            for (int r = 0; r < 4; ++r) {                                      \
                const float mu1 = m1[r], mu2 = m2[r];                          \
                const float ms  = fmaf(mu1, mu1, mu2 * mu2);                   \
                const float m12 = mu1 * mu2;                                   \
                const float s12 = pt[r] - m12;                                 \
                const float ssm = qq[r] - ms;                                  \
                const float num = fmaf(2.f, m12, C1) * fmaf(2.f, s12, C2);     \
                const float den = (ms + C1) * (ssm + C2);                      \
                sum += num * __builtin_amdgcn_rcpf(den);                       \
            }                                                                  \
        }                                                                      \
    }

    // ---- Prologue: stage tile 0 into A. ----
    STAGE(t0, stageA);
    VMCNT0(); BAR();

    // ---- Main loop: 2 tiles per iteration, static ping-pong A/B. ----
    #pragma unroll 1
    for (int i = 0; i < NT; i += 2) {
        STAGE(t0 + i + 1, stageB);          // i+1 <= NT-1 always (NT even)
        COMPUTE(stageA);
        VMCNT0(); BAR();                    // B fully staged; A free
        if (i + 2 < NT) STAGE(t0 + i + 2, stageA);
        COMPUTE(stageB);
        VMCNT0(); BAR();                    // A fully staged (or no-op last iter)
    }

    // ---- Reduce: wave -> block -> one atomic per block. ----
    #pragma unroll
    for (int off = 32; off > 0; off >>= 1) sum += __shfl_down(sum, off, 64);
    if (lane == 0) wsum[wv] = sum;
    __syncthreads();
    if (tid == 0) {
        float bs = 0.f;
        #pragma unroll
        for (int w2 = 0; w2 < 8; ++w2) bs += wsum[w2];
        atomicAdd(&acc[blockIdx.x & (NACC - 1)], bs);
    }
#undef STAGE
#undef COMPUTE
}

__global__ void ssim_final(const float* __restrict__ acc, float* __restrict__ out) {
    float s = 0.f;
    #pragma unroll
    for (int i = 0; i < NACC; ++i) s += acc[i];
    out[0] = 0.1f * (1.0f - s / NPIX);
}

extern "C" void kernel_launch(void* const* d_in, const int* in_sizes, int n_in,
                              void* d_out, int out_size, void* d_ws, size_t ws_size,
                              hipStream_t stream) {
    const float* pred = (const float*)d_in[0];
    const float* targ = (const float*)d_in[1];
    const float* win  = (const float*)d_in[2];
    float* out = (float*)d_out;
    float* ws  = (float*)d_ws;

    // 512B: 64 accumulator slots + 256B zero page (DMA source for OOB lanes).
    hipMemsetAsync(ws, 0, 512, stream);
    ssim_main<<<256, 512, 0, stream>>>(pred, targ, win, ws);
    ssim_final<<<1, 1, 0, stream>>>(ws, out);
}